// Round 1
// baseline (299.347 us; speedup 1.0000x reference)
//
#include <hip/hip_runtime.h>
#include <hip/hip_bf16.h>
#include <math.h>

#define NN     3072
#define NF     128
#define NHID   64
#define HEADS  8
#define LEN    8
#define NPATH  2048
#define NTK    4
#define NELEM  (NPATH*LEN)     // 16384
#define MAXDEG 128
#define SH     16              // 2 sets * 8 heads

// ---------------- init: zero histogram + scalar outputs ----------------
__global__ void k_init(int* __restrict__ hist, float* __restrict__ out) {
    int i = blockIdx.x * blockDim.x + threadIdx.x;
    if (i < NN) hist[i] = 0;
    if (i == 0) { out[NPATH] = 0.f; out[NPATH + 1] = 0.f; }
}

// ---------------- CSR build: one wave (64 threads) per row ----------------
__global__ void k_csr(const float* __restrict__ adj, int* __restrict__ cols,
                      int* __restrict__ cnt) {
    int row  = blockIdx.x;
    int lane = threadIdx.x;           // block = 64 threads
    const float* ar = adj + (size_t)row * NN;
    int* cr = cols + (size_t)row * MAXDEG;
    int base = 0;
    for (int c0 = 0; c0 < NN; c0 += 64) {
        int j = c0 + lane;
        bool pred = ar[j] > 0.f;
        unsigned long long b = __ballot(pred);
        int before = __popcll(b & ((1ull << lane) - 1ull));
        if (pred && (base + before) < MAXDEG) cr[base + before] = j;
        base += __popcll(b);
    }
    if (lane == 0) cnt[row] = base < MAXDEG ? base : MAXDEG;
}

// ---------------- Wh = features @ W  for all 16 (set,head) ----------------
// grid (48 row-tiles, 16 set*head), block 256; 64x64 tile, K=128 in chunks of 32
__global__ void k_gemm_wh(const float* __restrict__ feat,
                          const float* __restrict__ Wp, const float* __restrict__ Ws,
                          float* __restrict__ wh) {
    __shared__ float Fs[64][33];
    __shared__ float Wsh[32][64];
    int rt = blockIdx.x;
    int sh = blockIdx.y;
    int set = sh >> 3, head = sh & 7;
    const float* W = (set ? Ws : Wp) + (size_t)head * NF * NHID;  // [128][64]
    int tid = threadIdx.x;
    int tc = (tid & 15) * 4;
    int tr = (tid >> 4) * 4;
    float acc[4][4] = {};
    for (int k0 = 0; k0 < NF; k0 += 32) {
        for (int i = tid; i < 64 * 32; i += 256) {
            int r = i >> 5, k = i & 31;
            Fs[r][k] = feat[(size_t)(rt * 64 + r) * NF + k0 + k];
        }
        for (int i = tid; i < 32 * 64; i += 256) {
            int k = i >> 6, c = i & 63;
            Wsh[k][c] = W[(size_t)(k0 + k) * NHID + c];
        }
        __syncthreads();
        #pragma unroll
        for (int k = 0; k < 32; ++k) {
            float a0 = Fs[tr][k],   a1 = Fs[tr+1][k];
            float a2 = Fs[tr+2][k], a3 = Fs[tr+3][k];
            float b0 = Wsh[k][tc],   b1 = Wsh[k][tc+1];
            float b2 = Wsh[k][tc+2], b3 = Wsh[k][tc+3];
            acc[0][0]+=a0*b0; acc[0][1]+=a0*b1; acc[0][2]+=a0*b2; acc[0][3]+=a0*b3;
            acc[1][0]+=a1*b0; acc[1][1]+=a1*b1; acc[1][2]+=a1*b2; acc[1][3]+=a1*b3;
            acc[2][0]+=a2*b0; acc[2][1]+=a2*b1; acc[2][2]+=a2*b2; acc[2][3]+=a2*b3;
            acc[3][0]+=a3*b0; acc[3][1]+=a3*b1; acc[3][2]+=a3*b2; acc[3][3]+=a3*b3;
        }
        __syncthreads();
    }
    for (int i = 0; i < 4; ++i)
        for (int j = 0; j < 4; ++j)
            wh[((size_t)sh * NN + rt * 64 + tr + i) * NHID + tc + j] = acc[i][j];
}

// ---------------- f1 = Wh @ a[:64], f2 = Wh @ a[64:] ----------------
__global__ void k_f1f2(const float* __restrict__ wh, const float* __restrict__ ap,
                       const float* __restrict__ as_, float* __restrict__ f1,
                       float* __restrict__ f2) {
    int t = blockIdx.x * blockDim.x + threadIdx.x;
    if (t >= SH * NN) return;
    int sh = t / NN;
    int set = sh >> 3, head = sh & 7;
    const float* a = (set ? as_ : ap) + (size_t)head * 2 * NHID;
    const float* row = wh + (size_t)t * NHID;
    float s1 = 0.f, s2 = 0.f;
    for (int k = 0; k < NHID; ++k) { float v = row[k]; s1 += v * a[k]; s2 += v * a[NHID + k]; }
    f1[t] = s1; f2[t] = s2;
}

// ---------------- sparse GAT softmax + aggregation: 1 wave per (sh,node) ----------------
__global__ void k_gat(const float* __restrict__ wh, const float* __restrict__ f1a,
                      const float* __restrict__ f2a, const int* __restrict__ cols,
                      const int* __restrict__ cnt, float* __restrict__ xo) {
    __shared__ float att[4][MAXDEG];
    int lw = threadIdx.x >> 6;
    int lane = threadIdx.x & 63;
    int w = blockIdx.x * 4 + lw;           // 0 .. 16*3072-1
    int node = w % NN;
    int sh = w / NN;
    int deg = cnt[node];
    const int* cl = cols + (size_t)node * MAXDEG;
    float f1v = f1a[(size_t)sh * NN + node];
    const float* f2p = f2a + (size_t)sh * NN;

    float ev[2];
    float m = -1e30f;
    #pragma unroll
    for (int t = 0; t < 2; ++t) {
        int l = lane + t * 64;
        float e = -1e30f;
        if (l < deg) {
            int j = cl[l];
            e = f1v + f2p[j];
            e = (e >= 0.f) ? e : 0.2f * e;
        }
        ev[t] = e;
        m = fmaxf(m, e);
    }
    for (int o = 32; o; o >>= 1) m = fmaxf(m, __shfl_xor(m, o));
    float s = 0.f;
    #pragma unroll
    for (int t = 0; t < 2; ++t) {
        int l = lane + t * 64;
        float ex = (l < deg) ? expf(ev[t] - m) : 0.f;
        att[lw][l] = ex;
        s += ex;
    }
    for (int o = 32; o; o >>= 1) s += __shfl_xor(s, o);
    float inv = 1.f / s;

    const float* whp = wh + (size_t)sh * NN * NHID;
    float acc = 0.f;
    for (int l = 0; l < deg; ++l) {
        int j = cl[l];
        acc += att[lw][l] * whp[(size_t)j * NHID + lane];
    }
    acc *= inv;
    acc = (acc > 0.f) ? acc : (expf(acc) - 1.f);   // ELU
    int set = sh >> 3, head = sh & 7;
    xo[((size_t)set * NN + node) * (HEADS * NHID) + head * NHID + lane] = acc;
}

// ---------------- per-node logp for adversarial loss ----------------
__global__ void k_nlogp(const float* __restrict__ S, const float* __restrict__ Wsc,
                        const float* __restrict__ bsc, float* __restrict__ nlogp) {
    int w = blockIdx.x * 4 + (threadIdx.x >> 6);
    int lane = threadIdx.x & 63;
    if (w >= NN) return;
    const float* row = S + (size_t)w * (HEADS * NHID);
    float p[4] = {0.f, 0.f, 0.f, 0.f};
    for (int k = lane; k < HEADS * NHID; k += 64) {
        float v = row[k];
        p[0] += v * Wsc[k * 4 + 0];
        p[1] += v * Wsc[k * 4 + 1];
        p[2] += v * Wsc[k * 4 + 2];
        p[3] += v * Wsc[k * 4 + 3];
    }
    for (int o = 32; o; o >>= 1) {
        p[0] += __shfl_xor(p[0], o); p[1] += __shfl_xor(p[1], o);
        p[2] += __shfl_xor(p[2], o); p[3] += __shfl_xor(p[3], o);
    }
    if (lane == 0) {
        float sg[4], mx = -1e30f;
        for (int j = 0; j < 4; ++j) {
            sg[j] = 1.f / (1.f + expf(-(p[j] + bsc[j])));
            mx = fmaxf(mx, sg[j]);
        }
        float ex[4], se = 0.f;
        for (int j = 0; j < 4; ++j) { ex[j] = expf(sg[j] - mx); se += ex[j]; }
        float pr[4], pe = 0.f;
        for (int j = 0; j < 4; ++j) { pr[j] = ex[j] / se; }
        for (int j = 0; j < 4; ++j) { pe += expf(pr[j]); }
        float lse = logf(pe);
        for (int j = 0; j < 4; ++j) nlogp[(size_t)w * 4 + j] = pr[j] - lse;
    }
}

// ---------------- adversarial loss (single block) ----------------
__global__ void k_adv(const float* __restrict__ nlogp, const int* __restrict__ path,
                      const int* __restrict__ task, float* __restrict__ out) {
    __shared__ float red[256];
    float s = 0.f;
    for (int i = threadIdx.x; i < NELEM; i += 256) {
        int node = path[i];
        s += nlogp[(size_t)node * 4 + task[i]];
    }
    red[threadIdx.x] = s;
    __syncthreads();
    for (int o = 128; o; o >>= 1) {
        if (threadIdx.x < o) red[threadIdx.x] += red[threadIdx.x + o];
        __syncthreads();
    }
    if (threadIdx.x == 0) out[NPATH] = -red[0] / (float)NELEM;
}

// ---------------- node histogram ----------------
__global__ void k_hist(const int* __restrict__ path, int* __restrict__ hist) {
    int i = blockIdx.x * blockDim.x + threadIdx.x;
    if (i < NELEM) atomicAdd(&hist[path[i]], 1);
}

// ---------------- diff_loss: ||S^T diag(c) P||_F^2 ----------------
// grid (16,16), block 256; 32x32 output tile, K=3072 in chunks of 64
__global__ void k_diff(const float* __restrict__ S, const float* __restrict__ P,
                       const int* __restrict__ hist, float* __restrict__ out) {
    __shared__ float As[64][33];
    __shared__ float Bs[64][33];
    __shared__ float red[256];
    int a0 = blockIdx.y * 32, b0 = blockIdx.x * 32;
    int tr = (threadIdx.x >> 4) * 2, tc = (threadIdx.x & 15) * 2;
    float a00 = 0.f, a01 = 0.f, a10 = 0.f, a11 = 0.f;
    for (int k0 = 0; k0 < NN; k0 += 64) {
        for (int i = threadIdx.x; i < 64 * 32; i += 256) {
            int k = i >> 5, a = i & 31;
            float wgt = (float)hist[k0 + k];
            As[k][a] = S[(size_t)(k0 + k) * 512 + a0 + a] * wgt;
            Bs[k][a] = P[(size_t)(k0 + k) * 512 + b0 + a];
        }
        __syncthreads();
        #pragma unroll
        for (int k = 0; k < 64; ++k) {
            float x0 = As[k][tr], x1 = As[k][tr + 1];
            float y0 = Bs[k][tc], y1 = Bs[k][tc + 1];
            a00 += x0 * y0; a01 += x0 * y1; a10 += x1 * y0; a11 += x1 * y1;
        }
        __syncthreads();
    }
    float loc = a00 * a00 + a01 * a01 + a10 * a10 + a11 * a11;
    red[threadIdx.x] = loc;
    __syncthreads();
    for (int o = 128; o; o >>= 1) {
        if (threadIdx.x < o) red[threadIdx.x] += red[threadIdx.x + o];
        __syncthreads();
    }
    if (threadIdx.x == 0) atomicAdd(&out[NPATH + 1], red[0]);
}

// ---------------- final classifier x = sigmoid([S|P]_path @ Wc + bc) ----------------
__global__ void k_final(const float* __restrict__ S, const float* __restrict__ P,
                        const int* __restrict__ path, const float* __restrict__ Wc,
                        const float* __restrict__ bc, float* __restrict__ out) {
    __shared__ float red[256];
    int p = blockIdx.x;
    float s = 0.f;
    for (int m = threadIdx.x; m < 8192; m += 256) {
        int l = m >> 10, w = m & 1023;
        int node = path[p * LEN + l];
        float v = (w < 512) ? S[(size_t)node * 512 + w]
                            : P[(size_t)node * 512 + (w - 512)];
        s += v * Wc[m];
    }
    red[threadIdx.x] = s;
    __syncthreads();
    for (int o = 128; o; o >>= 1) {
        if (threadIdx.x < o) red[threadIdx.x] += red[threadIdx.x + o];
        __syncthreads();
    }
    if (threadIdx.x == 0) out[p] = 1.f / (1.f + expf(-(red[0] + bc[0])));
}

extern "C" void kernel_launch(void* const* d_in, const int* in_sizes, int n_in,
                              void* d_out, int out_size, void* d_ws, size_t ws_size,
                              hipStream_t stream) {
    const float* feat = (const float*)d_in[0];
    const float* adj  = (const float*)d_in[1];
    const int*   path = (const int*)d_in[2];
    const int*   task = (const int*)d_in[3];
    const float* Wp   = (const float*)d_in[4];
    const float* ap   = (const float*)d_in[5];
    const float* Ws   = (const float*)d_in[6];
    const float* as_  = (const float*)d_in[7];
    const float* Wsc  = (const float*)d_in[8];
    const float* bsc  = (const float*)d_in[9];
    const float* Wc   = (const float*)d_in[10];
    const float* bc   = (const float*)d_in[11];
    float* out = (float*)d_out;

    // workspace layout
    float* wh    = (float*)d_ws;                 // 16*3072*64 = 3145728
    float* f1    = wh + (size_t)SH * NN * NHID;  // 49152
    float* f2    = f1 + (size_t)SH * NN;         // 49152
    float* xo    = f2 + (size_t)SH * NN;         // 2*3072*512 = 3145728
    float* nlogp = xo + (size_t)2 * NN * 512;    // 12288
    int*   cols  = (int*)(nlogp + (size_t)NN * 4); // 393216 ints
    int*   cnt   = cols + (size_t)NN * MAXDEG;   // 3072
    int*   hist  = cnt + NN;                     // 3072

    float* Pm = xo;                        // private (set 0)
    float* Sm = xo + (size_t)NN * 512;     // share   (set 1)

    k_init<<<(NN + 255) / 256, 256, 0, stream>>>(hist, out);
    k_csr<<<NN, 64, 0, stream>>>(adj, cols, cnt);
    k_gemm_wh<<<dim3(NN / 64, SH), 256, 0, stream>>>(feat, Wp, Ws, wh);
    k_f1f2<<<(SH * NN + 255) / 256, 256, 0, stream>>>(wh, ap, as_, f1, f2);
    k_gat<<<SH * NN / 4, 256, 0, stream>>>(wh, f1, f2, cols, cnt, xo);
    k_nlogp<<<NN / 4, 256, 0, stream>>>(Sm, Wsc, bsc, nlogp);
    k_hist<<<(NELEM + 255) / 256, 256, 0, stream>>>(path, hist);
    k_adv<<<1, 256, 0, stream>>>(nlogp, path, task, out);
    k_diff<<<dim3(16, 16), 256, 0, stream>>>(Sm, Pm, hist, out);
    k_final<<<NPATH, 256, 0, stream>>>(Sm, Pm, path, Wc, bc, out);
}

// Round 2
// 209.745 us; speedup vs baseline: 1.4272x; 1.4272x over previous
//
#include <hip/hip_runtime.h>
#include <hip/hip_bf16.h>
#include <math.h>

#define NN     3072
#define NF     128
#define NHID   64
#define HEADS  8
#define LEN    8
#define NPATH  2048
#define NTK    4
#define NELEM  (NPATH*LEN)     // 16384
#define MAXDEG 128
#define SH     16              // 2 sets * 8 heads
#define KSPLIT 12
#define KCH    (NN / KSPLIT)   // 256

// ---------------- init: zero histogram + scalar outputs ----------------
__global__ void k_init(int* __restrict__ hist, float* __restrict__ out) {
    int i = blockIdx.x * blockDim.x + threadIdx.x;
    if (i < NN) hist[i] = 0;
    if (i == 0) { out[NPATH] = 0.f; out[NPATH + 1] = 0.f; }
}

// ---------------- CSR build: one wave (64 threads) per row ----------------
__global__ void k_csr(const float* __restrict__ adj, int* __restrict__ cols,
                      int* __restrict__ cnt) {
    int row  = blockIdx.x;
    int lane = threadIdx.x;           // block = 64 threads
    const float* ar = adj + (size_t)row * NN;
    int* cr = cols + (size_t)row * MAXDEG;
    int base = 0;
    for (int c0 = 0; c0 < NN; c0 += 64) {
        int j = c0 + lane;
        bool pred = ar[j] > 0.f;
        unsigned long long b = __ballot(pred);
        int before = __popcll(b & ((1ull << lane) - 1ull));
        if (pred && (base + before) < MAXDEG) cr[base + before] = j;
        base += __popcll(b);
    }
    if (lane == 0) cnt[row] = base < MAXDEG ? base : MAXDEG;
}

// ---------------- Wh = features @ W  for all 16 (set,head) ----------------
__global__ void k_gemm_wh(const float* __restrict__ feat,
                          const float* __restrict__ Wp, const float* __restrict__ Ws,
                          float* __restrict__ wh) {
    __shared__ float Fs[64][33];
    __shared__ float Wsh[32][64];
    int rt = blockIdx.x;
    int sh = blockIdx.y;
    int set = sh >> 3, head = sh & 7;
    const float* W = (set ? Ws : Wp) + (size_t)head * NF * NHID;  // [128][64]
    int tid = threadIdx.x;
    int tc = (tid & 15) * 4;
    int tr = (tid >> 4) * 4;
    float acc[4][4] = {};
    for (int k0 = 0; k0 < NF; k0 += 32) {
        for (int i = tid; i < 64 * 32; i += 256) {
            int r = i >> 5, k = i & 31;
            Fs[r][k] = feat[(size_t)(rt * 64 + r) * NF + k0 + k];
        }
        for (int i = tid; i < 32 * 64; i += 256) {
            int k = i >> 6, c = i & 63;
            Wsh[k][c] = W[(size_t)(k0 + k) * NHID + c];
        }
        __syncthreads();
        #pragma unroll
        for (int k = 0; k < 32; ++k) {
            float a0 = Fs[tr][k],   a1 = Fs[tr+1][k];
            float a2 = Fs[tr+2][k], a3 = Fs[tr+3][k];
            float b0 = Wsh[k][tc],   b1 = Wsh[k][tc+1];
            float b2 = Wsh[k][tc+2], b3 = Wsh[k][tc+3];
            acc[0][0]+=a0*b0; acc[0][1]+=a0*b1; acc[0][2]+=a0*b2; acc[0][3]+=a0*b3;
            acc[1][0]+=a1*b0; acc[1][1]+=a1*b1; acc[1][2]+=a1*b2; acc[1][3]+=a1*b3;
            acc[2][0]+=a2*b0; acc[2][1]+=a2*b1; acc[2][2]+=a2*b2; acc[2][3]+=a2*b3;
            acc[3][0]+=a3*b0; acc[3][1]+=a3*b1; acc[3][2]+=a3*b2; acc[3][3]+=a3*b3;
        }
        __syncthreads();
    }
    for (int i = 0; i < 4; ++i)
        for (int j = 0; j < 4; ++j)
            wh[((size_t)sh * NN + rt * 64 + tr + i) * NHID + tc + j] = acc[i][j];
}

// ---------------- f1 = Wh @ a[:64], f2 = Wh @ a[64:] ----------------
__global__ void k_f1f2(const float* __restrict__ wh, const float* __restrict__ ap,
                       const float* __restrict__ as_, float* __restrict__ f1,
                       float* __restrict__ f2) {
    int t = blockIdx.x * blockDim.x + threadIdx.x;
    if (t >= SH * NN) return;
    int sh = t / NN;
    int set = sh >> 3, head = sh & 7;
    const float* a = (set ? as_ : ap) + (size_t)head * 2 * NHID;
    const float* row = wh + (size_t)t * NHID;
    float s1 = 0.f, s2 = 0.f;
    for (int k = 0; k < NHID; ++k) { float v = row[k]; s1 += v * a[k]; s2 += v * a[NHID + k]; }
    f1[t] = s1; f2[t] = s2;
}

// ---------------- sparse GAT softmax + aggregation: 1 wave per (sh,node) ----------------
__global__ void k_gat(const float* __restrict__ wh, const float* __restrict__ f1a,
                      const float* __restrict__ f2a, const int* __restrict__ cols,
                      const int* __restrict__ cnt, float* __restrict__ xo) {
    __shared__ float att[4][MAXDEG];
    int lw = threadIdx.x >> 6;
    int lane = threadIdx.x & 63;
    int w = blockIdx.x * 4 + lw;           // 0 .. 16*3072-1
    int node = w % NN;
    int sh = w / NN;
    int deg = cnt[node];
    const int* cl = cols + (size_t)node * MAXDEG;
    float f1v = f1a[(size_t)sh * NN + node];
    const float* f2p = f2a + (size_t)sh * NN;

    float ev[2];
    float m = -1e30f;
    #pragma unroll
    for (int t = 0; t < 2; ++t) {
        int l = lane + t * 64;
        float e = -1e30f;
        if (l < deg) {
            int j = cl[l];
            e = f1v + f2p[j];
            e = (e >= 0.f) ? e : 0.2f * e;
        }
        ev[t] = e;
        m = fmaxf(m, e);
    }
    for (int o = 32; o; o >>= 1) m = fmaxf(m, __shfl_xor(m, o));
    float s = 0.f;
    #pragma unroll
    for (int t = 0; t < 2; ++t) {
        int l = lane + t * 64;
        float ex = (l < deg) ? expf(ev[t] - m) : 0.f;
        att[lw][l] = ex;
        s += ex;
    }
    for (int o = 32; o; o >>= 1) s += __shfl_xor(s, o);
    float inv = 1.f / s;

    const float* whp = wh + (size_t)sh * NN * NHID;
    float acc = 0.f;
    for (int l = 0; l < deg; ++l) {
        int j = cl[l];
        acc += att[lw][l] * whp[(size_t)j * NHID + lane];
    }
    acc *= inv;
    acc = (acc > 0.f) ? acc : (expf(acc) - 1.f);   // ELU
    int set = sh >> 3, head = sh & 7;
    xo[((size_t)set * NN + node) * (HEADS * NHID) + head * NHID + lane] = acc;
}

// ---------------- per-node logp for adversarial loss ----------------
__global__ void k_nlogp(const float* __restrict__ S, const float* __restrict__ Wsc,
                        const float* __restrict__ bsc, float* __restrict__ nlogp) {
    int w = blockIdx.x * 4 + (threadIdx.x >> 6);
    int lane = threadIdx.x & 63;
    if (w >= NN) return;
    const float* row = S + (size_t)w * (HEADS * NHID);
    float p[4] = {0.f, 0.f, 0.f, 0.f};
    for (int k = lane; k < HEADS * NHID; k += 64) {
        float v = row[k];
        p[0] += v * Wsc[k * 4 + 0];
        p[1] += v * Wsc[k * 4 + 1];
        p[2] += v * Wsc[k * 4 + 2];
        p[3] += v * Wsc[k * 4 + 3];
    }
    for (int o = 32; o; o >>= 1) {
        p[0] += __shfl_xor(p[0], o); p[1] += __shfl_xor(p[1], o);
        p[2] += __shfl_xor(p[2], o); p[3] += __shfl_xor(p[3], o);
    }
    if (lane == 0) {
        float sg[4], mx = -1e30f;
        for (int j = 0; j < 4; ++j) {
            sg[j] = 1.f / (1.f + expf(-(p[j] + bsc[j])));
            mx = fmaxf(mx, sg[j]);
        }
        float ex[4], se = 0.f;
        for (int j = 0; j < 4; ++j) { ex[j] = expf(sg[j] - mx); se += ex[j]; }
        float pr[4], pe = 0.f;
        for (int j = 0; j < 4; ++j) { pr[j] = ex[j] / se; }
        for (int j = 0; j < 4; ++j) { pe += expf(pr[j]); }
        float lse = logf(pe);
        for (int j = 0; j < 4; ++j) nlogp[(size_t)w * 4 + j] = pr[j] - lse;
    }
}

// ---------------- adversarial loss (single block) ----------------
__global__ void k_adv(const float* __restrict__ nlogp, const int* __restrict__ path,
                      const int* __restrict__ task, float* __restrict__ out) {
    __shared__ float red[256];
    float s = 0.f;
    for (int i = threadIdx.x; i < NELEM; i += 256) {
        int node = path[i];
        s += nlogp[(size_t)node * 4 + task[i]];
    }
    red[threadIdx.x] = s;
    __syncthreads();
    for (int o = 128; o; o >>= 1) {
        if (threadIdx.x < o) red[threadIdx.x] += red[threadIdx.x + o];
        __syncthreads();
    }
    if (threadIdx.x == 0) out[NPATH] = -red[0] / (float)NELEM;
}

// ---------------- node histogram ----------------
__global__ void k_hist(const int* __restrict__ path, int* __restrict__ hist) {
    int i = blockIdx.x * blockDim.x + threadIdx.x;
    if (i < NELEM) atomicAdd(&hist[path[i]], 1);
}

// ---------------- diff partial: D += S^T diag(c) P over one K-chunk ----------------
// grid (8,8,KSPLIT), block 256; 64x64 output tile, K-chunk 256
__global__ void k_diff_part(const float* __restrict__ S, const float* __restrict__ P,
                            const int* __restrict__ hist, float* __restrict__ D) {
    __shared__ float As[64][68];
    __shared__ float Bs[64][68];
    int a0 = blockIdx.y * 64, b0 = blockIdx.x * 64;
    int kbase = blockIdx.z * KCH;
    int tr = (threadIdx.x >> 4) * 4, tc = (threadIdx.x & 15) * 4;
    float acc[4][4] = {};
    for (int k0 = 0; k0 < KCH; k0 += 64) {
        for (int i = threadIdx.x; i < 64 * 16; i += 256) {
            int k = i >> 4, c4 = (i & 15) * 4;
            int krow = kbase + k0 + k;
            float wgt = (float)hist[krow];
            float4 sv = *(const float4*)&S[(size_t)krow * 512 + a0 + c4];
            As[k][c4 + 0] = sv.x * wgt; As[k][c4 + 1] = sv.y * wgt;
            As[k][c4 + 2] = sv.z * wgt; As[k][c4 + 3] = sv.w * wgt;
            float4 pv = *(const float4*)&P[(size_t)krow * 512 + b0 + c4];
            Bs[k][c4 + 0] = pv.x; Bs[k][c4 + 1] = pv.y;
            Bs[k][c4 + 2] = pv.z; Bs[k][c4 + 3] = pv.w;
        }
        __syncthreads();
        #pragma unroll
        for (int k = 0; k < 64; ++k) {
            float a_[4], b_[4];
            #pragma unroll
            for (int i = 0; i < 4; ++i) a_[i] = As[k][tr + i];
            #pragma unroll
            for (int j = 0; j < 4; ++j) b_[j] = Bs[k][tc + j];
            #pragma unroll
            for (int i = 0; i < 4; ++i)
                #pragma unroll
                for (int j = 0; j < 4; ++j) acc[i][j] += a_[i] * b_[j];
        }
        __syncthreads();
    }
    #pragma unroll
    for (int i = 0; i < 4; ++i)
        #pragma unroll
        for (int j = 0; j < 4; ++j)
            atomicAdd(&D[(size_t)(a0 + tr + i) * 512 + b0 + tc + j], acc[i][j]);
}

// ---------------- diff reduce: out += sum(D^2) ----------------
__global__ void k_diff_red(const float* __restrict__ D, float* __restrict__ out) {
    __shared__ float red[256];
    float s = 0.f;
    for (int i = blockIdx.x * 256 + threadIdx.x; i < 512 * 512; i += gridDim.x * 256) {
        float v = D[i];
        s += v * v;
    }
    red[threadIdx.x] = s;
    __syncthreads();
    for (int o = 128; o; o >>= 1) {
        if (threadIdx.x < o) red[threadIdx.x] += red[threadIdx.x + o];
        __syncthreads();
    }
    if (threadIdx.x == 0) atomicAdd(&out[NPATH + 1], red[0]);
}

// ---------------- final classifier x = sigmoid([S|P]_path @ Wc + bc) ----------------
__global__ void k_final(const float* __restrict__ S, const float* __restrict__ P,
                        const int* __restrict__ path, const float* __restrict__ Wc,
                        const float* __restrict__ bc, float* __restrict__ out) {
    __shared__ float red[256];
    int p = blockIdx.x;
    float s = 0.f;
    for (int m4 = threadIdx.x; m4 < 2048; m4 += 256) {
        int m = m4 * 4;
        int l = m >> 10, w = m & 1023;
        int node = path[p * LEN + l];
        float4 wv = *(const float4*)&Wc[m];
        const float* src = (w < 512) ? &S[(size_t)node * 512 + w]
                                     : &P[(size_t)node * 512 + (w - 512)];
        float4 xv = *(const float4*)src;
        s += xv.x * wv.x + xv.y * wv.y + xv.z * wv.z + xv.w * wv.w;
    }
    red[threadIdx.x] = s;
    __syncthreads();
    for (int o = 128; o; o >>= 1) {
        if (threadIdx.x < o) red[threadIdx.x] += red[threadIdx.x + o];
        __syncthreads();
    }
    if (threadIdx.x == 0) out[p] = 1.f / (1.f + expf(-(red[0] + bc[0])));
}

extern "C" void kernel_launch(void* const* d_in, const int* in_sizes, int n_in,
                              void* d_out, int out_size, void* d_ws, size_t ws_size,
                              hipStream_t stream) {
    const float* feat = (const float*)d_in[0];
    const float* adj  = (const float*)d_in[1];
    const int*   path = (const int*)d_in[2];
    const int*   task = (const int*)d_in[3];
    const float* Wp   = (const float*)d_in[4];
    const float* ap   = (const float*)d_in[5];
    const float* Ws   = (const float*)d_in[6];
    const float* as_  = (const float*)d_in[7];
    const float* Wsc  = (const float*)d_in[8];
    const float* bsc  = (const float*)d_in[9];
    const float* Wc   = (const float*)d_in[10];
    const float* bc   = (const float*)d_in[11];
    float* out = (float*)d_out;

    // workspace layout
    float* wh    = (float*)d_ws;                 // 16*3072*64 = 3145728
    float* f1    = wh + (size_t)SH * NN * NHID;  // 49152
    float* f2    = f1 + (size_t)SH * NN;         // 49152
    float* xo    = f2 + (size_t)SH * NN;         // 2*3072*512 = 3145728
    float* nlogp = xo + (size_t)2 * NN * 512;    // 12288
    float* D     = nlogp + (size_t)NN * 4;       // 512*512 = 262144
    int*   cols  = (int*)(D + 512 * 512);        // 393216 ints
    int*   cnt   = cols + (size_t)NN * MAXDEG;   // 3072
    int*   hist  = cnt + NN;                     // 3072

    float* Pm = xo;                        // private (set 0)
    float* Sm = xo + (size_t)NN * 512;     // share   (set 1)

    k_init<<<(NN + 255) / 256, 256, 0, stream>>>(hist, out);
    hipMemsetAsync(D, 0, 512 * 512 * sizeof(float), stream);
    k_csr<<<NN, 64, 0, stream>>>(adj, cols, cnt);
    k_gemm_wh<<<dim3(NN / 64, SH), 256, 0, stream>>>(feat, Wp, Ws, wh);
    k_f1f2<<<(SH * NN + 255) / 256, 256, 0, stream>>>(wh, ap, as_, f1, f2);
    k_gat<<<SH * NN / 4, 256, 0, stream>>>(wh, f1, f2, cols, cnt, xo);
    k_nlogp<<<NN / 4, 256, 0, stream>>>(Sm, Wsc, bsc, nlogp);
    k_hist<<<(NELEM + 255) / 256, 256, 0, stream>>>(path, hist);
    k_adv<<<1, 256, 0, stream>>>(nlogp, path, task, out);
    k_diff_part<<<dim3(8, 8, KSPLIT), 256, 0, stream>>>(Sm, Pm, hist, D);
    k_diff_red<<<64, 256, 0, stream>>>(D, out);
    k_final<<<NPATH, 256, 0, stream>>>(Sm, Pm, path, Wc, bc, out);
}

// Round 3
// 175.393 us; speedup vs baseline: 1.7067x; 1.1959x over previous
//
#include <hip/hip_runtime.h>
#include <hip/hip_bf16.h>
#include <math.h>

#define NN     3072
#define NF     128
#define NHID   64
#define HEADS  8
#define LEN    8
#define NPATH  2048
#define NTK    4
#define NELEM  (NPATH*LEN)     // 16384
#define MAXDEG 128
#define SH     16              // 2 sets * 8 heads
#define KSPLIT 12
#define KCH    (NN / KSPLIT)   // 256

// ---------------- init: zero histograms + scalar outputs ----------------
__global__ void k_init(int* __restrict__ hist, int* __restrict__ histT,
                       float* __restrict__ out) {
    int i = blockIdx.x * blockDim.x + threadIdx.x;
    if (i < NN) hist[i] = 0;
    if (i < NN * NTK) histT[i] = 0;
    if (i == 0) { out[NPATH] = 0.f; out[NPATH + 1] = 0.f; }
}

// ---------------- CSR build: one wave per row, float4 scan ----------------
__global__ void k_csr(const float* __restrict__ adj, int* __restrict__ cols,
                      int* __restrict__ cnt) {
    int row  = blockIdx.x;
    int lane = threadIdx.x;           // block = 64 threads
    const float* ar = adj + (size_t)row * NN;
    int* cr = cols + (size_t)row * MAXDEG;
    int base = 0;
    for (int c0 = 0; c0 < NN; c0 += 256) {
        float4 v = *(const float4*)&ar[c0 + lane * 4];
        float e[4] = {v.x, v.y, v.z, v.w};
        #pragma unroll
        for (int q = 0; q < 4; ++q) {
            bool pred = e[q] > 0.f;
            unsigned long long b = __ballot(pred);
            int before = __popcll(b & ((1ull << lane) - 1ull));
            if (pred && (base + before) < MAXDEG) cr[base + before] = c0 + lane * 4 + q;
            base += __popcll(b);
        }
    }
    if (lane == 0) cnt[row] = base < MAXDEG ? base : MAXDEG;
}

// ---------------- Wh = features @ W  for all 16 (set,head) ----------------
// grid (48, 16), block 256; 64x64 tile, K=128 in chunks of 32, float4 LDS reads
__global__ void k_gemm_wh(const float* __restrict__ feat,
                          const float* __restrict__ Wp, const float* __restrict__ Ws,
                          float* __restrict__ wh) {
    __shared__ float Fs[32][68];   // [k][r], padded stride keeps 16B alignment
    __shared__ float Wsh[32][64];  // [k][c]
    int rt = blockIdx.x;
    int sh = blockIdx.y;
    int set = sh >> 3, head = sh & 7;
    const float* W = (set ? Ws : Wp) + (size_t)head * NF * NHID;  // [128][64]
    int tid = threadIdx.x;
    int tc = (tid & 15) * 4;
    int tr = (tid >> 4) * 4;
    float acc[4][4] = {};
    for (int k0 = 0; k0 < NF; k0 += 32) {
        // feat tile (transposed into LDS): rows rt*64..+64, cols k0..k0+32
        for (int i = tid; i < 512; i += 256) {
            int r = i >> 3, kq = (i & 7) * 4;
            float4 v = *(const float4*)&feat[(size_t)(rt * 64 + r) * NF + k0 + kq];
            Fs[kq + 0][r] = v.x; Fs[kq + 1][r] = v.y;
            Fs[kq + 2][r] = v.z; Fs[kq + 3][r] = v.w;
        }
        // W tile
        for (int i = tid; i < 512; i += 256) {
            int k = i >> 4, cq = (i & 15) * 4;
            *(float4*)&Wsh[k][cq] = *(const float4*)&W[(size_t)(k0 + k) * NHID + cq];
        }
        __syncthreads();
        #pragma unroll
        for (int k = 0; k < 32; ++k) {
            float4 a = *(const float4*)&Fs[k][tr];
            float4 b = *(const float4*)&Wsh[k][tc];
            float a_[4] = {a.x, a.y, a.z, a.w};
            float b_[4] = {b.x, b.y, b.z, b.w};
            #pragma unroll
            for (int i = 0; i < 4; ++i)
                #pragma unroll
                for (int j = 0; j < 4; ++j) acc[i][j] += a_[i] * b_[j];
        }
        __syncthreads();
    }
    for (int i = 0; i < 4; ++i)
        *(float4*)&wh[((size_t)sh * NN + rt * 64 + tr + i) * NHID + tc] =
            *(float4*)&acc[i][0];
}

// ---------------- f1 = Wh @ a[:64], f2 = Wh @ a[64:] ----------------
__global__ void k_f1f2(const float* __restrict__ wh, const float* __restrict__ ap,
                       const float* __restrict__ as_, float* __restrict__ f1,
                       float* __restrict__ f2) {
    int t = blockIdx.x * blockDim.x + threadIdx.x;
    if (t >= SH * NN) return;
    int sh = t / NN;
    int set = sh >> 3, head = sh & 7;
    const float* a = (set ? as_ : ap) + (size_t)head * 2 * NHID;
    const float* row = wh + (size_t)t * NHID;
    float s1 = 0.f, s2 = 0.f;
    for (int k = 0; k < NHID; k += 4) {
        float4 v = *(const float4*)&row[k];
        float4 a1 = *(const float4*)&a[k];
        float4 a2 = *(const float4*)&a[NHID + k];
        s1 += v.x * a1.x + v.y * a1.y + v.z * a1.z + v.w * a1.w;
        s2 += v.x * a2.x + v.y * a2.y + v.z * a2.z + v.w * a2.w;
    }
    f1[t] = s1; f2[t] = s2;
}

// ---------------- sparse GAT softmax + aggregation: 1 wave per (sh,node) ----------------
__global__ void k_gat(const float* __restrict__ wh, const float* __restrict__ f1a,
                      const float* __restrict__ f2a, const int* __restrict__ cols,
                      const int* __restrict__ cnt, float* __restrict__ xo) {
    __shared__ float att[4][MAXDEG];
    int lw = threadIdx.x >> 6;
    int lane = threadIdx.x & 63;
    int w = blockIdx.x * 4 + lw;           // 0 .. 16*3072-1
    int node = w % NN;
    int sh = w / NN;
    int deg = cnt[node];
    const int* cl = cols + (size_t)node * MAXDEG;
    float f1v = f1a[(size_t)sh * NN + node];
    const float* f2p = f2a + (size_t)sh * NN;

    float ev[2];
    float m = -1e30f;
    #pragma unroll
    for (int t = 0; t < 2; ++t) {
        int l = lane + t * 64;
        float e = -1e30f;
        if (l < deg) {
            int j = cl[l];
            e = f1v + f2p[j];
            e = (e >= 0.f) ? e : 0.2f * e;
        }
        ev[t] = e;
        m = fmaxf(m, e);
    }
    for (int o = 32; o; o >>= 1) m = fmaxf(m, __shfl_xor(m, o));
    float s = 0.f;
    #pragma unroll
    for (int t = 0; t < 2; ++t) {
        int l = lane + t * 64;
        float ex = (l < deg) ? expf(ev[t] - m) : 0.f;
        att[lw][l] = ex;
        s += ex;
    }
    for (int o = 32; o; o >>= 1) s += __shfl_xor(s, o);
    float inv = 1.f / s;

    const float* whp = wh + (size_t)sh * NN * NHID;
    float acc = 0.f;
    for (int l = 0; l < deg; ++l) {
        int j = cl[l];
        acc += att[lw][l] * whp[(size_t)j * NHID + lane];
    }
    acc *= inv;
    acc = (acc > 0.f) ? acc : (expf(acc) - 1.f);   // ELU
    int set = sh >> 3, head = sh & 7;
    xo[((size_t)set * NN + node) * (HEADS * NHID) + head * NHID + lane] = acc;
}

// ---------------- node + (node,task) histograms ----------------
__global__ void k_hist(const int* __restrict__ path, const int* __restrict__ task,
                       int* __restrict__ hist, int* __restrict__ histT) {
    int i = blockIdx.x * blockDim.x + threadIdx.x;
    if (i < NELEM) {
        int node = path[i];
        atomicAdd(&hist[node], 1);
        atomicAdd(&histT[node * NTK + task[i]], 1);
    }
}

// ---------------- per-node logp + fused adversarial loss ----------------
__global__ void k_nlogp(const float* __restrict__ S, const float* __restrict__ Wsc,
                        const float* __restrict__ bsc, const int* __restrict__ histT,
                        float* __restrict__ out) {
    int w = blockIdx.x * 4 + (threadIdx.x >> 6);
    int lane = threadIdx.x & 63;
    if (w >= NN) return;
    const float* row = S + (size_t)w * (HEADS * NHID);
    float p[4] = {0.f, 0.f, 0.f, 0.f};
    for (int k = lane; k < HEADS * NHID; k += 64) {
        float v = row[k];
        p[0] += v * Wsc[k * 4 + 0];
        p[1] += v * Wsc[k * 4 + 1];
        p[2] += v * Wsc[k * 4 + 2];
        p[3] += v * Wsc[k * 4 + 3];
    }
    for (int o = 32; o; o >>= 1) {
        p[0] += __shfl_xor(p[0], o); p[1] += __shfl_xor(p[1], o);
        p[2] += __shfl_xor(p[2], o); p[3] += __shfl_xor(p[3], o);
    }
    if (lane == 0) {
        float sg[4], mx = -1e30f;
        for (int j = 0; j < 4; ++j) {
            sg[j] = 1.f / (1.f + expf(-(p[j] + bsc[j])));
            mx = fmaxf(mx, sg[j]);
        }
        float ex[4], se = 0.f;
        for (int j = 0; j < 4; ++j) { ex[j] = expf(sg[j] - mx); se += ex[j]; }
        float pr[4], pe = 0.f;
        for (int j = 0; j < 4; ++j) { pr[j] = ex[j] / se; }
        for (int j = 0; j < 4; ++j) { pe += expf(pr[j]); }
        float lse = logf(pe);
        float s = 0.f;
        for (int j = 0; j < 4; ++j) s += (float)histT[w * NTK + j] * (pr[j] - lse);
        if (s != 0.f) atomicAdd(&out[NPATH], -s * (1.f / (float)NELEM));
    }
}

// ---------------- diff partial: Dp[z] = S^T diag(c) P over one K-chunk ----------------
// grid (8,8,KSPLIT), block 256; 64x64 output tile, K-chunk 256, NO atomics
__global__ void k_diff_part(const float* __restrict__ S, const float* __restrict__ P,
                            const int* __restrict__ hist, float* __restrict__ Dp) {
    __shared__ float As[64][68];
    __shared__ float Bs[64][68];
    int a0 = blockIdx.y * 64, b0 = blockIdx.x * 64;
    int kbase = blockIdx.z * KCH;
    int tr = (threadIdx.x >> 4) * 4, tc = (threadIdx.x & 15) * 4;
    float acc[4][4] = {};
    for (int k0 = 0; k0 < KCH; k0 += 64) {
        for (int i = threadIdx.x; i < 64 * 16; i += 256) {
            int k = i >> 4, c4 = (i & 15) * 4;
            int krow = kbase + k0 + k;
            float wgt = (float)hist[krow];
            float4 sv = *(const float4*)&S[(size_t)krow * 512 + a0 + c4];
            As[k][c4 + 0] = sv.x * wgt; As[k][c4 + 1] = sv.y * wgt;
            As[k][c4 + 2] = sv.z * wgt; As[k][c4 + 3] = sv.w * wgt;
            float4 pv = *(const float4*)&P[(size_t)krow * 512 + b0 + c4];
            Bs[k][c4 + 0] = pv.x; Bs[k][c4 + 1] = pv.y;
            Bs[k][c4 + 2] = pv.z; Bs[k][c4 + 3] = pv.w;
        }
        __syncthreads();
        #pragma unroll
        for (int k = 0; k < 64; ++k) {
            float4 av = *(const float4*)&As[k][tr];
            float4 bv = *(const float4*)&Bs[k][tc];
            float a_[4] = {av.x, av.y, av.z, av.w};
            float b_[4] = {bv.x, bv.y, bv.z, bv.w};
            #pragma unroll
            for (int i = 0; i < 4; ++i)
                #pragma unroll
                for (int j = 0; j < 4; ++j) acc[i][j] += a_[i] * b_[j];
        }
        __syncthreads();
    }
    float* dst = Dp + (size_t)blockIdx.z * 512 * 512;
    #pragma unroll
    for (int i = 0; i < 4; ++i)
        *(float4*)&dst[(size_t)(a0 + tr + i) * 512 + b0 + tc] = *(float4*)&acc[i][0];
}

// ---------------- diff reduce: out += sum((sum_z Dp[z])^2) ----------------
__global__ void k_diff_red(const float* __restrict__ Dp, float* __restrict__ out) {
    __shared__ float red[256];
    int e4 = blockIdx.x * 256 + threadIdx.x;   // float4 index, 65536 total
    float4 a = {0.f, 0.f, 0.f, 0.f};
    for (int z = 0; z < KSPLIT; ++z) {
        float4 v = *(const float4*)&Dp[(size_t)z * 512 * 512 + (size_t)e4 * 4];
        a.x += v.x; a.y += v.y; a.z += v.z; a.w += v.w;
    }
    red[threadIdx.x] = a.x * a.x + a.y * a.y + a.z * a.z + a.w * a.w;
    __syncthreads();
    for (int o = 128; o; o >>= 1) {
        if (threadIdx.x < o) red[threadIdx.x] += red[threadIdx.x + o];
        __syncthreads();
    }
    if (threadIdx.x == 0) atomicAdd(&out[NPATH + 1], red[0]);
}

// ---------------- final classifier x = sigmoid([S|P]_path @ Wc + bc) ----------------
__global__ void k_final(const float* __restrict__ S, const float* __restrict__ P,
                        const int* __restrict__ path, const float* __restrict__ Wc,
                        const float* __restrict__ bc, float* __restrict__ out) {
    __shared__ float red[256];
    int p = blockIdx.x;
    float s = 0.f;
    for (int m4 = threadIdx.x; m4 < 2048; m4 += 256) {
        int m = m4 * 4;
        int l = m >> 10, w = m & 1023;
        int node = path[p * LEN + l];
        float4 wv = *(const float4*)&Wc[m];
        const float* src = (w < 512) ? &S[(size_t)node * 512 + w]
                                     : &P[(size_t)node * 512 + (w - 512)];
        float4 xv = *(const float4*)src;
        s += xv.x * wv.x + xv.y * wv.y + xv.z * wv.z + xv.w * wv.w;
    }
    red[threadIdx.x] = s;
    __syncthreads();
    for (int o = 128; o; o >>= 1) {
        if (threadIdx.x < o) red[threadIdx.x] += red[threadIdx.x + o];
        __syncthreads();
    }
    if (threadIdx.x == 0) out[p] = 1.f / (1.f + expf(-(red[0] + bc[0])));
}

extern "C" void kernel_launch(void* const* d_in, const int* in_sizes, int n_in,
                              void* d_out, int out_size, void* d_ws, size_t ws_size,
                              hipStream_t stream) {
    const float* feat = (const float*)d_in[0];
    const float* adj  = (const float*)d_in[1];
    const int*   path = (const int*)d_in[2];
    const int*   task = (const int*)d_in[3];
    const float* Wp   = (const float*)d_in[4];
    const float* ap   = (const float*)d_in[5];
    const float* Ws   = (const float*)d_in[6];
    const float* as_  = (const float*)d_in[7];
    const float* Wsc  = (const float*)d_in[8];
    const float* bsc  = (const float*)d_in[9];
    const float* Wc   = (const float*)d_in[10];
    const float* bc   = (const float*)d_in[11];
    float* out = (float*)d_out;

    // workspace layout
    float* wh    = (float*)d_ws;                   // 16*3072*64 = 3,145,728
    float* f1    = wh + (size_t)SH * NN * NHID;    // 49,152
    float* f2    = f1 + (size_t)SH * NN;           // 49,152
    float* xo    = f2 + (size_t)SH * NN;           // 2*3072*512 = 3,145,728
    float* Dp    = xo + (size_t)2 * NN * 512;      // KSPLIT*512*512 = 3,145,728
    int*   cols  = (int*)(Dp + (size_t)KSPLIT * 512 * 512); // 393,216
    int*   cnt   = cols + (size_t)NN * MAXDEG;     // 3,072
    int*   hist  = cnt + NN;                       // 3,072
    int*   histT = hist + NN;                      // 12,288

    float* Pm = xo;                        // private (set 0)
    float* Sm = xo + (size_t)NN * 512;     // share   (set 1)

    k_init<<<(NN * NTK + 255) / 256, 256, 0, stream>>>(hist, histT, out);
    k_csr<<<NN, 64, 0, stream>>>(adj, cols, cnt);
    k_gemm_wh<<<dim3(NN / 64, SH), 256, 0, stream>>>(feat, Wp, Ws, wh);
    k_f1f2<<<(SH * NN + 255) / 256, 256, 0, stream>>>(wh, ap, as_, f1, f2);
    k_gat<<<SH * NN / 4, 256, 0, stream>>>(wh, f1, f2, cols, cnt, xo);
    k_hist<<<(NELEM + 255) / 256, 256, 0, stream>>>(path, task, hist, histT);
    k_nlogp<<<NN / 4, 256, 0, stream>>>(Sm, Wsc, bsc, histT, out);
    k_diff_part<<<dim3(8, 8, KSPLIT), 256, 0, stream>>>(Sm, Pm, hist, Dp);
    k_diff_red<<<256, 256, 0, stream>>>(Dp, out);
    k_final<<<NPATH, 256, 0, stream>>>(Sm, Pm, path, Wc, bc, out);
}

// Round 4
// 162.327 us; speedup vs baseline: 1.8441x; 1.0805x over previous
//
#include <hip/hip_runtime.h>
#include <hip/hip_bf16.h>
#include <math.h>

#define NN     3072
#define NF     128
#define NHID   64
#define HEADS  8
#define LEN    8
#define NPATH  2048
#define NTK    4
#define NELEM  (NPATH*LEN)     // 16384
#define MAXDEG 128
#define SH     16              // 2 sets * 8 heads
#define KSPLIT 12
#define KCH    (NN / KSPLIT)   // 256

// ---------------- init: zero histograms + scalar outputs ----------------
__global__ void k_init(int* __restrict__ hist, int* __restrict__ histT,
                       float* __restrict__ out) {
    int i = blockIdx.x * blockDim.x + threadIdx.x;
    if (i < NN) hist[i] = 0;
    if (i < NN * NTK) histT[i] = 0;
    if (i == 0) { out[NPATH] = 0.f; out[NPATH + 1] = 0.f; }
}

// ---------------- CSR build: one wave per row, 4 rows/block, float4 scan ----------------
__global__ void k_csr(const float* __restrict__ adj, int* __restrict__ cols,
                      int* __restrict__ cnt) {
    int row  = blockIdx.x * 4 + (threadIdx.x >> 6);
    int lane = threadIdx.x & 63;
    const float* ar = adj + (size_t)row * NN;
    int* cr = cols + (size_t)row * MAXDEG;
    int base = 0;
    for (int c0 = 0; c0 < NN; c0 += 256) {
        float4 v = *(const float4*)&ar[c0 + lane * 4];
        float e[4] = {v.x, v.y, v.z, v.w};
        #pragma unroll
        for (int q = 0; q < 4; ++q) {
            bool pred = e[q] > 0.f;
            unsigned long long b = __ballot(pred);
            int before = __popcll(b & ((1ull << lane) - 1ull));
            if (pred && (base + before) < MAXDEG) cr[base + before] = c0 + lane * 4 + q;
            base += __popcll(b);
        }
    }
    if (lane == 0) cnt[row] = base < MAXDEG ? base : MAXDEG;
}

// ---------------- Wh = features @ W (+ fused f1/f2 epilogue) ----------------
// grid (48, 16), block 256; 64x64 tile, K=128 in chunks of 32
__global__ void k_gemm_wh(const float* __restrict__ feat,
                          const float* __restrict__ Wp, const float* __restrict__ Ws,
                          const float* __restrict__ ap, const float* __restrict__ as_,
                          float* __restrict__ wh, float* __restrict__ f1,
                          float* __restrict__ f2) {
    __shared__ float Fs[32][68];   // [k][r]
    __shared__ float Wsh[32][64];  // [k][c]
    int rt = blockIdx.x;
    int sh = blockIdx.y;
    int set = sh >> 3, head = sh & 7;
    const float* W = (set ? Ws : Wp) + (size_t)head * NF * NHID;  // [128][64]
    const float* a = (set ? as_ : ap) + (size_t)head * 2 * NHID;
    int tid = threadIdx.x;
    int tc = (tid & 15) * 4;
    int tr = (tid >> 4) * 4;
    float acc[4][4] = {};
    for (int k0 = 0; k0 < NF; k0 += 32) {
        for (int i = tid; i < 512; i += 256) {
            int r = i >> 3, kq = (i & 7) * 4;
            float4 v = *(const float4*)&feat[(size_t)(rt * 64 + r) * NF + k0 + kq];
            Fs[kq + 0][r] = v.x; Fs[kq + 1][r] = v.y;
            Fs[kq + 2][r] = v.z; Fs[kq + 3][r] = v.w;
        }
        for (int i = tid; i < 512; i += 256) {
            int k = i >> 4, cq = (i & 15) * 4;
            *(float4*)&Wsh[k][cq] = *(const float4*)&W[(size_t)(k0 + k) * NHID + cq];
        }
        __syncthreads();
        #pragma unroll
        for (int k = 0; k < 32; ++k) {
            float4 av = *(const float4*)&Fs[k][tr];
            float4 bv = *(const float4*)&Wsh[k][tc];
            float a_[4] = {av.x, av.y, av.z, av.w};
            float b_[4] = {bv.x, bv.y, bv.z, bv.w};
            #pragma unroll
            for (int i = 0; i < 4; ++i)
                #pragma unroll
                for (int j = 0; j < 4; ++j) acc[i][j] += a_[i] * b_[j];
        }
        __syncthreads();
    }
    for (int i = 0; i < 4; ++i)
        *(float4*)&wh[((size_t)sh * NN + rt * 64 + tr + i) * NHID + tc] =
            *(float4*)&acc[i][0];
    // fused f1/f2: per-thread partial over its 4 columns, reduce across the
    // 16 lanes (same tid>>4) that share the 4 rows
    float4 a1 = *(const float4*)&a[tc];
    float4 a2 = *(const float4*)&a[NHID + tc];
    float p1[4], p2[4];
    #pragma unroll
    for (int i = 0; i < 4; ++i) {
        p1[i] = acc[i][0] * a1.x + acc[i][1] * a1.y + acc[i][2] * a1.z + acc[i][3] * a1.w;
        p2[i] = acc[i][0] * a2.x + acc[i][1] * a2.y + acc[i][2] * a2.z + acc[i][3] * a2.w;
    }
    #pragma unroll
    for (int o = 1; o < 16; o <<= 1) {
        #pragma unroll
        for (int i = 0; i < 4; ++i) {
            p1[i] += __shfl_xor(p1[i], o);
            p2[i] += __shfl_xor(p2[i], o);
        }
    }
    if ((tid & 15) == 0) {
        #pragma unroll
        for (int i = 0; i < 4; ++i) {
            f1[(size_t)sh * NN + rt * 64 + tr + i] = p1[i];
            f2[(size_t)sh * NN + rt * 64 + tr + i] = p2[i];
        }
    }
}

// ---------------- sparse GAT: 1 wave per (sh,node), XCD-grouped by sh ----------------
__global__ void k_gat(const float* __restrict__ wh, const float* __restrict__ f1a,
                      const float* __restrict__ f2a, const int* __restrict__ cols,
                      const int* __restrict__ cnt, float* __restrict__ xo) {
    __shared__ float att[4][MAXDEG];
    int lw = threadIdx.x >> 6;
    int lane = threadIdx.x & 63;
    // XCD-aware: blocks with same (bid&7) land on the same XCD (round-robin);
    // give each XCD only 2 of the 16 sh so wh[sh] fits its private L2.
    int bid = blockIdx.x;                 // 0 .. 12287
    int q = bid >> 3;                     // 0 .. 1535
    int sh = (bid & 7) + ((q / 768) << 3);
    int node = (q % 768) * 4 + lw;
    int deg = cnt[node];
    const int* cl = cols + (size_t)node * MAXDEG;
    float f1v = f1a[(size_t)sh * NN + node];
    const float* f2p = f2a + (size_t)sh * NN;

    float ev[2];
    float m = -1e30f;
    #pragma unroll
    for (int t = 0; t < 2; ++t) {
        int l = lane + t * 64;
        float e = -1e30f;
        if (l < deg) {
            int j = cl[l];
            e = f1v + f2p[j];
            e = (e >= 0.f) ? e : 0.2f * e;
        }
        ev[t] = e;
        m = fmaxf(m, e);
    }
    for (int o = 32; o; o >>= 1) m = fmaxf(m, __shfl_xor(m, o));
    float s = 0.f;
    #pragma unroll
    for (int t = 0; t < 2; ++t) {
        int l = lane + t * 64;
        float ex = (l < deg) ? expf(ev[t] - m) : 0.f;
        att[lw][l] = ex;
        s += ex;
    }
    for (int o = 32; o; o >>= 1) s += __shfl_xor(s, o);
    float inv = 1.f / s;

    const float* whp = wh + (size_t)sh * NN * NHID;
    float acc0 = 0.f, acc1 = 0.f, acc2 = 0.f, acc3 = 0.f;
    int l = 0;
    for (; l + 4 <= deg; l += 4) {
        int j0 = cl[l], j1 = cl[l + 1], j2 = cl[l + 2], j3 = cl[l + 3];
        float w0 = att[lw][l],     w1 = att[lw][l + 1];
        float w2 = att[lw][l + 2], w3 = att[lw][l + 3];
        acc0 += w0 * whp[(size_t)j0 * NHID + lane];
        acc1 += w1 * whp[(size_t)j1 * NHID + lane];
        acc2 += w2 * whp[(size_t)j2 * NHID + lane];
        acc3 += w3 * whp[(size_t)j3 * NHID + lane];
    }
    for (; l < deg; ++l) acc0 += att[lw][l] * whp[(size_t)cl[l] * NHID + lane];
    float acc = ((acc0 + acc1) + (acc2 + acc3)) * inv;
    acc = (acc > 0.f) ? acc : (expf(acc) - 1.f);   // ELU
    int set = sh >> 3, head = sh & 7;
    xo[((size_t)set * NN + node) * (HEADS * NHID) + head * NHID + lane] = acc;
}

// ---------------- node + (node,task) histograms ----------------
__global__ void k_hist(const int* __restrict__ path, const int* __restrict__ task,
                       int* __restrict__ hist, int* __restrict__ histT) {
    int i = blockIdx.x * blockDim.x + threadIdx.x;
    if (i < NELEM) {
        int node = path[i];
        atomicAdd(&hist[node], 1);
        atomicAdd(&histT[node * NTK + task[i]], 1);
    }
}

// ---------------- per-node logp + fused adversarial loss ----------------
__global__ void k_nlogp(const float* __restrict__ S, const float* __restrict__ Wsc,
                        const float* __restrict__ bsc, const int* __restrict__ histT,
                        float* __restrict__ out) {
    int w = blockIdx.x * 4 + (threadIdx.x >> 6);
    int lane = threadIdx.x & 63;
    if (w >= NN) return;
    const float* row = S + (size_t)w * (HEADS * NHID);
    float p[4] = {0.f, 0.f, 0.f, 0.f};
    for (int k = lane; k < HEADS * NHID; k += 64) {
        float v = row[k];
        p[0] += v * Wsc[k * 4 + 0];
        p[1] += v * Wsc[k * 4 + 1];
        p[2] += v * Wsc[k * 4 + 2];
        p[3] += v * Wsc[k * 4 + 3];
    }
    for (int o = 32; o; o >>= 1) {
        p[0] += __shfl_xor(p[0], o); p[1] += __shfl_xor(p[1], o);
        p[2] += __shfl_xor(p[2], o); p[3] += __shfl_xor(p[3], o);
    }
    if (lane == 0) {
        float sg[4], mx = -1e30f;
        for (int j = 0; j < 4; ++j) {
            sg[j] = 1.f / (1.f + expf(-(p[j] + bsc[j])));
            mx = fmaxf(mx, sg[j]);
        }
        float ex[4], se = 0.f;
        for (int j = 0; j < 4; ++j) { ex[j] = expf(sg[j] - mx); se += ex[j]; }
        float pr[4], pe = 0.f;
        for (int j = 0; j < 4; ++j) { pr[j] = ex[j] / se; }
        for (int j = 0; j < 4; ++j) { pe += expf(pr[j]); }
        float lse = logf(pe);
        float s = 0.f;
        for (int j = 0; j < 4; ++j) s += (float)histT[w * NTK + j] * (pr[j] - lse);
        if (s != 0.f) atomicAdd(&out[NPATH], -s * (1.f / (float)NELEM));
    }
}

// ---------------- diff partial: Dp[z] = S^T diag(c) P over one K-chunk ----------------
__global__ void k_diff_part(const float* __restrict__ S, const float* __restrict__ P,
                            const int* __restrict__ hist, float* __restrict__ Dp) {
    __shared__ float As[64][68];
    __shared__ float Bs[64][68];
    int a0 = blockIdx.y * 64, b0 = blockIdx.x * 64;
    int kbase = blockIdx.z * KCH;
    int tr = (threadIdx.x >> 4) * 4, tc = (threadIdx.x & 15) * 4;
    float acc[4][4] = {};
    for (int k0 = 0; k0 < KCH; k0 += 64) {
        for (int i = threadIdx.x; i < 64 * 16; i += 256) {
            int k = i >> 4, c4 = (i & 15) * 4;
            int krow = kbase + k0 + k;
            float wgt = (float)hist[krow];
            float4 sv = *(const float4*)&S[(size_t)krow * 512 + a0 + c4];
            As[k][c4 + 0] = sv.x * wgt; As[k][c4 + 1] = sv.y * wgt;
            As[k][c4 + 2] = sv.z * wgt; As[k][c4 + 3] = sv.w * wgt;
            float4 pv = *(const float4*)&P[(size_t)krow * 512 + b0 + c4];
            Bs[k][c4 + 0] = pv.x; Bs[k][c4 + 1] = pv.y;
            Bs[k][c4 + 2] = pv.z; Bs[k][c4 + 3] = pv.w;
        }
        __syncthreads();
        #pragma unroll
        for (int k = 0; k < 64; ++k) {
            float4 av = *(const float4*)&As[k][tr];
            float4 bv = *(const float4*)&Bs[k][tc];
            float a_[4] = {av.x, av.y, av.z, av.w};
            float b_[4] = {bv.x, bv.y, bv.z, bv.w};
            #pragma unroll
            for (int i = 0; i < 4; ++i)
                #pragma unroll
                for (int j = 0; j < 4; ++j) acc[i][j] += a_[i] * b_[j];
        }
        __syncthreads();
    }
    float* dst = Dp + (size_t)blockIdx.z * 512 * 512;
    #pragma unroll
    for (int i = 0; i < 4; ++i)
        *(float4*)&dst[(size_t)(a0 + tr + i) * 512 + b0 + tc] = *(float4*)&acc[i][0];
}

// ---------------- diff reduce: out += sum((sum_z Dp[z])^2) ----------------
__global__ void k_diff_red(const float* __restrict__ Dp, float* __restrict__ out) {
    __shared__ float red[256];
    int e4 = blockIdx.x * 256 + threadIdx.x;   // float4 index, 65536 total
    float4 a = {0.f, 0.f, 0.f, 0.f};
    for (int z = 0; z < KSPLIT; ++z) {
        float4 v = *(const float4*)&Dp[(size_t)z * 512 * 512 + (size_t)e4 * 4];
        a.x += v.x; a.y += v.y; a.z += v.z; a.w += v.w;
    }
    red[threadIdx.x] = a.x * a.x + a.y * a.y + a.z * a.z + a.w * a.w;
    __syncthreads();
    for (int o = 128; o; o >>= 1) {
        if (threadIdx.x < o) red[threadIdx.x] += red[threadIdx.x + o];
        __syncthreads();
    }
    if (threadIdx.x == 0) atomicAdd(&out[NPATH + 1], red[0]);
}

// ---------------- final classifier x = sigmoid([S|P]_path @ Wc + bc) ----------------
__global__ void k_final(const float* __restrict__ S, const float* __restrict__ P,
                        const int* __restrict__ path, const float* __restrict__ Wc,
                        const float* __restrict__ bc, float* __restrict__ out) {
    __shared__ float red[256];
    int p = blockIdx.x;
    float s = 0.f;
    for (int m4 = threadIdx.x; m4 < 2048; m4 += 256) {
        int m = m4 * 4;
        int l = m >> 10, w = m & 1023;
        int node = path[p * LEN + l];
        float4 wv = *(const float4*)&Wc[m];
        const float* src = (w < 512) ? &S[(size_t)node * 512 + w]
                                     : &P[(size_t)node * 512 + (w - 512)];
        float4 xv = *(const float4*)src;
        s += xv.x * wv.x + xv.y * wv.y + xv.z * wv.z + xv.w * wv.w;
    }
    red[threadIdx.x] = s;
    __syncthreads();
    for (int o = 128; o; o >>= 1) {
        if (threadIdx.x < o) red[threadIdx.x] += red[threadIdx.x + o];
        __syncthreads();
    }
    if (threadIdx.x == 0) out[p] = 1.f / (1.f + expf(-(red[0] + bc[0])));
}

extern "C" void kernel_launch(void* const* d_in, const int* in_sizes, int n_in,
                              void* d_out, int out_size, void* d_ws, size_t ws_size,
                              hipStream_t stream) {
    const float* feat = (const float*)d_in[0];
    const float* adj  = (const float*)d_in[1];
    const int*   path = (const int*)d_in[2];
    const int*   task = (const int*)d_in[3];
    const float* Wp   = (const float*)d_in[4];
    const float* ap   = (const float*)d_in[5];
    const float* Ws   = (const float*)d_in[6];
    const float* as_  = (const float*)d_in[7];
    const float* Wsc  = (const float*)d_in[8];
    const float* bsc  = (const float*)d_in[9];
    const float* Wc   = (const float*)d_in[10];
    const float* bc   = (const float*)d_in[11];
    float* out = (float*)d_out;

    // workspace layout
    float* wh    = (float*)d_ws;                   // 16*3072*64
    float* f1    = wh + (size_t)SH * NN * NHID;
    float* f2    = f1 + (size_t)SH * NN;
    float* xo    = f2 + (size_t)SH * NN;           // 2*3072*512
    float* Dp    = xo + (size_t)2 * NN * 512;      // KSPLIT*512*512
    int*   cols  = (int*)(Dp + (size_t)KSPLIT * 512 * 512);
    int*   cnt   = cols + (size_t)NN * MAXDEG;
    int*   hist  = cnt + NN;
    int*   histT = hist + NN;

    float* Pm = xo;                        // private (set 0)
    float* Sm = xo + (size_t)NN * 512;     // share   (set 1)

    k_init<<<(NN * NTK + 255) / 256, 256, 0, stream>>>(hist, histT, out);
    k_hist<<<(NELEM + 255) / 256, 256, 0, stream>>>(path, task, hist, histT);
    k_csr<<<NN / 4, 256, 0, stream>>>(adj, cols, cnt);
    k_gemm_wh<<<dim3(NN / 64, SH), 256, 0, stream>>>(feat, Wp, Ws, ap, as_, wh, f1, f2);
    k_gat<<<SH * NN / 4, 256, 0, stream>>>(wh, f1, f2, cols, cnt, xo);
    k_nlogp<<<NN / 4, 256, 0, stream>>>(Sm, Wsc, bsc, histT, out);
    k_diff_part<<<dim3(8, 8, KSPLIT), 256, 0, stream>>>(Sm, Pm, hist, Dp);
    k_diff_red<<<256, 256, 0, stream>>>(Dp, out);
    k_final<<<NPATH, 256, 0, stream>>>(Sm, Pm, path, Wc, bc, out);
}

// Round 5
// 129.365 us; speedup vs baseline: 2.3140x; 1.2548x over previous
//
#include <hip/hip_runtime.h>
#include <hip/hip_bf16.h>
#include <math.h>

#define NN     3072
#define NF     128
#define NHID   64
#define HEADS  8
#define LEN    8
#define NPATH  2048
#define NTK    4
#define NELEM  (NPATH*LEN)     // 16384
#define MAXDEG 128
#define SH     16              // 2 sets * 8 heads
#define KSPLIT 12
#define KCH    (NN / KSPLIT)   // 256
#define NADV   192             // k_nlogp blocks
#define NDIF   256             // k_diff_red blocks

// ---------------- init: zero histograms ----------------
__global__ void k_init(int* __restrict__ hist, int* __restrict__ histT) {
    int i = blockIdx.x * blockDim.x + threadIdx.x;
    if (i < NN) hist[i] = 0;
    if (i < NN * NTK) histT[i] = 0;
}

// ---------------- CSR build: one wave per row, 4 rows/block, float4 scan ----------------
__global__ void k_csr(const float* __restrict__ adj, int* __restrict__ cols,
                      int* __restrict__ cnt) {
    int row  = blockIdx.x * 4 + (threadIdx.x >> 6);
    int lane = threadIdx.x & 63;
    const float* ar = adj + (size_t)row * NN;
    int* cr = cols + (size_t)row * MAXDEG;
    int base = 0;
    for (int c0 = 0; c0 < NN; c0 += 256) {
        float4 v = *(const float4*)&ar[c0 + lane * 4];
        float e[4] = {v.x, v.y, v.z, v.w};
        #pragma unroll
        for (int q = 0; q < 4; ++q) {
            bool pred = e[q] > 0.f;
            unsigned long long b = __ballot(pred);
            int before = __popcll(b & ((1ull << lane) - 1ull));
            if (pred && (base + before) < MAXDEG) cr[base + before] = c0 + lane * 4 + q;
            base += __popcll(b);
        }
    }
    if (lane == 0) cnt[row] = base < MAXDEG ? base : MAXDEG;
}

// ---------------- Wh = features @ W (+ fused f1/f2 epilogue) ----------------
__global__ void k_gemm_wh(const float* __restrict__ feat,
                          const float* __restrict__ Wp, const float* __restrict__ Ws,
                          const float* __restrict__ ap, const float* __restrict__ as_,
                          float* __restrict__ wh, float* __restrict__ f1,
                          float* __restrict__ f2) {
    __shared__ float Fs[32][68];   // [k][r]
    __shared__ float Wsh[32][64];  // [k][c]
    int rt = blockIdx.x;
    int sh = blockIdx.y;
    int set = sh >> 3, head = sh & 7;
    const float* W = (set ? Ws : Wp) + (size_t)head * NF * NHID;  // [128][64]
    const float* a = (set ? as_ : ap) + (size_t)head * 2 * NHID;
    int tid = threadIdx.x;
    int tc = (tid & 15) * 4;
    int tr = (tid >> 4) * 4;
    float acc[4][4] = {};
    for (int k0 = 0; k0 < NF; k0 += 32) {
        for (int i = tid; i < 512; i += 256) {
            int r = i >> 3, kq = (i & 7) * 4;
            float4 v = *(const float4*)&feat[(size_t)(rt * 64 + r) * NF + k0 + kq];
            Fs[kq + 0][r] = v.x; Fs[kq + 1][r] = v.y;
            Fs[kq + 2][r] = v.z; Fs[kq + 3][r] = v.w;
        }
        for (int i = tid; i < 512; i += 256) {
            int k = i >> 4, cq = (i & 15) * 4;
            *(float4*)&Wsh[k][cq] = *(const float4*)&W[(size_t)(k0 + k) * NHID + cq];
        }
        __syncthreads();
        #pragma unroll
        for (int k = 0; k < 32; ++k) {
            float4 av = *(const float4*)&Fs[k][tr];
            float4 bv = *(const float4*)&Wsh[k][tc];
            float a_[4] = {av.x, av.y, av.z, av.w};
            float b_[4] = {bv.x, bv.y, bv.z, bv.w};
            #pragma unroll
            for (int i = 0; i < 4; ++i)
                #pragma unroll
                for (int j = 0; j < 4; ++j) acc[i][j] += a_[i] * b_[j];
        }
        __syncthreads();
    }
    for (int i = 0; i < 4; ++i)
        *(float4*)&wh[((size_t)sh * NN + rt * 64 + tr + i) * NHID + tc] =
            *(float4*)&acc[i][0];
    float4 a1 = *(const float4*)&a[tc];
    float4 a2 = *(const float4*)&a[NHID + tc];
    float p1[4], p2[4];
    #pragma unroll
    for (int i = 0; i < 4; ++i) {
        p1[i] = acc[i][0] * a1.x + acc[i][1] * a1.y + acc[i][2] * a1.z + acc[i][3] * a1.w;
        p2[i] = acc[i][0] * a2.x + acc[i][1] * a2.y + acc[i][2] * a2.z + acc[i][3] * a2.w;
    }
    #pragma unroll
    for (int o = 1; o < 16; o <<= 1) {
        #pragma unroll
        for (int i = 0; i < 4; ++i) {
            p1[i] += __shfl_xor(p1[i], o);
            p2[i] += __shfl_xor(p2[i], o);
        }
    }
    if ((tid & 15) == 0) {
        #pragma unroll
        for (int i = 0; i < 4; ++i) {
            f1[(size_t)sh * NN + rt * 64 + tr + i] = p1[i];
            f2[(size_t)sh * NN + rt * 64 + tr + i] = p2[i];
        }
    }
}

// ---------------- sparse GAT: 1 wave per (sh,node), XCD-grouped by sh ----------------
__global__ void k_gat(const float* __restrict__ wh, const float* __restrict__ f1a,
                      const float* __restrict__ f2a, const int* __restrict__ cols,
                      const int* __restrict__ cnt, float* __restrict__ xo) {
    __shared__ float att[4][MAXDEG];
    int lw = threadIdx.x >> 6;
    int lane = threadIdx.x & 63;
    int bid = blockIdx.x;                 // 0 .. 12287
    int q = bid >> 3;                     // 0 .. 1535
    int sh = (bid & 7) + ((q / 768) << 3);
    int node = (q % 768) * 4 + lw;
    int deg = cnt[node];
    const int* cl = cols + (size_t)node * MAXDEG;
    float f1v = f1a[(size_t)sh * NN + node];
    const float* f2p = f2a + (size_t)sh * NN;

    float ev[2];
    float m = -1e30f;
    #pragma unroll
    for (int t = 0; t < 2; ++t) {
        int l = lane + t * 64;
        float e = -1e30f;
        if (l < deg) {
            int j = cl[l];
            e = f1v + f2p[j];
            e = (e >= 0.f) ? e : 0.2f * e;
        }
        ev[t] = e;
        m = fmaxf(m, e);
    }
    for (int o = 32; o; o >>= 1) m = fmaxf(m, __shfl_xor(m, o));
    float s = 0.f;
    #pragma unroll
    for (int t = 0; t < 2; ++t) {
        int l = lane + t * 64;
        float ex = (l < deg) ? expf(ev[t] - m) : 0.f;
        att[lw][l] = ex;
        s += ex;
    }
    for (int o = 32; o; o >>= 1) s += __shfl_xor(s, o);
    float inv = 1.f / s;

    const float* whp = wh + (size_t)sh * NN * NHID;
    float acc0 = 0.f, acc1 = 0.f, acc2 = 0.f, acc3 = 0.f;
    int l = 0;
    for (; l + 4 <= deg; l += 4) {
        int j0 = cl[l], j1 = cl[l + 1], j2 = cl[l + 2], j3 = cl[l + 3];
        float w0 = att[lw][l],     w1 = att[lw][l + 1];
        float w2 = att[lw][l + 2], w3 = att[lw][l + 3];
        acc0 += w0 * whp[(size_t)j0 * NHID + lane];
        acc1 += w1 * whp[(size_t)j1 * NHID + lane];
        acc2 += w2 * whp[(size_t)j2 * NHID + lane];
        acc3 += w3 * whp[(size_t)j3 * NHID + lane];
    }
    for (; l < deg; ++l) acc0 += att[lw][l] * whp[(size_t)cl[l] * NHID + lane];
    float acc = ((acc0 + acc1) + (acc2 + acc3)) * inv;
    acc = (acc > 0.f) ? acc : (expf(acc) - 1.f);   // ELU
    int set = sh >> 3, head = sh & 7;
    xo[((size_t)set * NN + node) * (HEADS * NHID) + head * NHID + lane] = acc;
}

// ---------------- node + (node,task) histograms ----------------
__global__ void k_hist(const int* __restrict__ path, const int* __restrict__ task,
                       int* __restrict__ hist, int* __restrict__ histT) {
    int i = blockIdx.x * blockDim.x + threadIdx.x;
    if (i < NELEM) {
        int node = path[i];
        atomicAdd(&hist[node], 1);
        atomicAdd(&histT[node * NTK + task[i]], 1);
    }
}

// ---------------- per-node logp + adv partials (NO same-address atomics) ----------------
// grid NADV=192 blocks; each block: 4 waves x 4 nodes
__global__ void k_nlogp(const float* __restrict__ S, const float* __restrict__ Wsc,
                        const float* __restrict__ bsc, const int* __restrict__ histT,
                        float* __restrict__ padv) {
    __shared__ float red[4];
    int wave = threadIdx.x >> 6;
    int lane = threadIdx.x & 63;
    float sloc = 0.f;
    #pragma unroll
    for (int i = 0; i < 4; ++i) {
        int w = blockIdx.x * 16 + wave * 4 + i;
        const float* row = S + (size_t)w * (HEADS * NHID);
        float4 v0 = *(const float4*)&row[lane * 8];
        float4 v1 = *(const float4*)&row[lane * 8 + 4];
        float vv[8] = {v0.x, v0.y, v0.z, v0.w, v1.x, v1.y, v1.z, v1.w};
        float p[4] = {0.f, 0.f, 0.f, 0.f};
        #pragma unroll
        for (int qq = 0; qq < 8; ++qq) {
            float4 wv = *(const float4*)&Wsc[(lane * 8 + qq) * 4];
            p[0] += vv[qq] * wv.x; p[1] += vv[qq] * wv.y;
            p[2] += vv[qq] * wv.z; p[3] += vv[qq] * wv.w;
        }
        for (int o = 32; o; o >>= 1) {
            p[0] += __shfl_xor(p[0], o); p[1] += __shfl_xor(p[1], o);
            p[2] += __shfl_xor(p[2], o); p[3] += __shfl_xor(p[3], o);
        }
        if (lane == 0) {
            float sg[4], mx = -1e30f;
            for (int j = 0; j < 4; ++j) {
                sg[j] = 1.f / (1.f + expf(-(p[j] + bsc[j])));
                mx = fmaxf(mx, sg[j]);
            }
            float ex[4], se = 0.f;
            for (int j = 0; j < 4; ++j) { ex[j] = expf(sg[j] - mx); se += ex[j]; }
            float pr[4], pe = 0.f;
            for (int j = 0; j < 4; ++j) { pr[j] = ex[j] / se; }
            for (int j = 0; j < 4; ++j) { pe += expf(pr[j]); }
            float lse = logf(pe);
            for (int j = 0; j < 4; ++j)
                sloc += (float)histT[w * NTK + j] * (pr[j] - lse);
        }
    }
    if (lane == 0) red[wave] = sloc;
    __syncthreads();
    if (threadIdx.x == 0)
        padv[blockIdx.x] = red[0] + red[1] + red[2] + red[3];
}

// ---------------- diff partial: Dp[z] = S^T diag(c) P over one K-chunk ----------------
__global__ void k_diff_part(const float* __restrict__ S, const float* __restrict__ P,
                            const int* __restrict__ hist, float* __restrict__ Dp) {
    __shared__ float As[64][68];
    __shared__ float Bs[64][68];
    int a0 = blockIdx.y * 64, b0 = blockIdx.x * 64;
    int kbase = blockIdx.z * KCH;
    int tr = (threadIdx.x >> 4) * 4, tc = (threadIdx.x & 15) * 4;
    float acc[4][4] = {};
    for (int k0 = 0; k0 < KCH; k0 += 64) {
        for (int i = threadIdx.x; i < 64 * 16; i += 256) {
            int k = i >> 4, c4 = (i & 15) * 4;
            int krow = kbase + k0 + k;
            float wgt = (float)hist[krow];
            float4 sv = *(const float4*)&S[(size_t)krow * 512 + a0 + c4];
            As[k][c4 + 0] = sv.x * wgt; As[k][c4 + 1] = sv.y * wgt;
            As[k][c4 + 2] = sv.z * wgt; As[k][c4 + 3] = sv.w * wgt;
            float4 pv = *(const float4*)&P[(size_t)krow * 512 + b0 + c4];
            Bs[k][c4 + 0] = pv.x; Bs[k][c4 + 1] = pv.y;
            Bs[k][c4 + 2] = pv.z; Bs[k][c4 + 3] = pv.w;
        }
        __syncthreads();
        #pragma unroll
        for (int k = 0; k < 64; ++k) {
            float4 av = *(const float4*)&As[k][tr];
            float4 bv = *(const float4*)&Bs[k][tc];
            float a_[4] = {av.x, av.y, av.z, av.w};
            float b_[4] = {bv.x, bv.y, bv.z, bv.w};
            #pragma unroll
            for (int i = 0; i < 4; ++i)
                #pragma unroll
                for (int j = 0; j < 4; ++j) acc[i][j] += a_[i] * b_[j];
        }
        __syncthreads();
    }
    float* dst = Dp + (size_t)blockIdx.z * 512 * 512;
    #pragma unroll
    for (int i = 0; i < 4; ++i)
        *(float4*)&dst[(size_t)(a0 + tr + i) * 512 + b0 + tc] = *(float4*)&acc[i][0];
}

// ---------------- diff reduce: pdiff[b] = partial sum((sum_z Dp[z])^2) ----------------
__global__ void k_diff_red(const float* __restrict__ Dp, float* __restrict__ pdiff) {
    __shared__ float red[256];
    int e4 = blockIdx.x * 256 + threadIdx.x;   // float4 index, 65536 total
    float4 a = {0.f, 0.f, 0.f, 0.f};
    for (int z = 0; z < KSPLIT; ++z) {
        float4 v = *(const float4*)&Dp[(size_t)z * 512 * 512 + (size_t)e4 * 4];
        a.x += v.x; a.y += v.y; a.z += v.z; a.w += v.w;
    }
    red[threadIdx.x] = a.x * a.x + a.y * a.y + a.z * a.z + a.w * a.w;
    __syncthreads();
    for (int o = 128; o; o >>= 1) {
        if (threadIdx.x < o) red[threadIdx.x] += red[threadIdx.x + o];
        __syncthreads();
    }
    if (threadIdx.x == 0) pdiff[blockIdx.x] = red[0];
}

// ---------------- final scalar outputs (single block; no atomics anywhere) ----------------
__global__ void k_scalars(const float* __restrict__ padv, const float* __restrict__ pdiff,
                          float* __restrict__ out) {
    __shared__ float red[256];
    int t = threadIdx.x;
    red[t] = (t < NADV) ? padv[t] : 0.f;
    __syncthreads();
    for (int o = 128; o; o >>= 1) {
        if (t < o) red[t] += red[t + o];
        __syncthreads();
    }
    if (t == 0) out[NPATH] = -red[0] * (1.f / (float)NELEM);
    __syncthreads();
    red[t] = pdiff[t];
    __syncthreads();
    for (int o = 128; o; o >>= 1) {
        if (t < o) red[t] += red[t + o];
        __syncthreads();
    }
    if (t == 0) out[NPATH + 1] = red[0];
}

// ---------------- final classifier x = sigmoid([S|P]_path @ Wc + bc) ----------------
__global__ void k_final(const float* __restrict__ S, const float* __restrict__ P,
                        const int* __restrict__ path, const float* __restrict__ Wc,
                        const float* __restrict__ bc, float* __restrict__ out) {
    __shared__ float red[256];
    int p = blockIdx.x;
    float s = 0.f;
    for (int m4 = threadIdx.x; m4 < 2048; m4 += 256) {
        int m = m4 * 4;
        int l = m >> 10, w = m & 1023;
        int node = path[p * LEN + l];
        float4 wv = *(const float4*)&Wc[m];
        const float* src = (w < 512) ? &S[(size_t)node * 512 + w]
                                     : &P[(size_t)node * 512 + (w - 512)];
        float4 xv = *(const float4*)src;
        s += xv.x * wv.x + xv.y * wv.y + xv.z * wv.z + xv.w * wv.w;
    }
    red[threadIdx.x] = s;
    __syncthreads();
    for (int o = 128; o; o >>= 1) {
        if (threadIdx.x < o) red[threadIdx.x] += red[threadIdx.x + o];
        __syncthreads();
    }
    if (threadIdx.x == 0) out[p] = 1.f / (1.f + expf(-(red[0] + bc[0])));
}

extern "C" void kernel_launch(void* const* d_in, const int* in_sizes, int n_in,
                              void* d_out, int out_size, void* d_ws, size_t ws_size,
                              hipStream_t stream) {
    const float* feat = (const float*)d_in[0];
    const float* adj  = (const float*)d_in[1];
    const int*   path = (const int*)d_in[2];
    const int*   task = (const int*)d_in[3];
    const float* Wp   = (const float*)d_in[4];
    const float* ap   = (const float*)d_in[5];
    const float* Ws   = (const float*)d_in[6];
    const float* as_  = (const float*)d_in[7];
    const float* Wsc  = (const float*)d_in[8];
    const float* bsc  = (const float*)d_in[9];
    const float* Wc   = (const float*)d_in[10];
    const float* bc   = (const float*)d_in[11];
    float* out = (float*)d_out;

    // workspace layout
    float* wh    = (float*)d_ws;                   // 16*3072*64
    float* f1    = wh + (size_t)SH * NN * NHID;
    float* f2    = f1 + (size_t)SH * NN;
    float* xo    = f2 + (size_t)SH * NN;           // 2*3072*512
    float* Dp    = xo + (size_t)2 * NN * 512;      // KSPLIT*512*512
    float* padv  = Dp + (size_t)KSPLIT * 512 * 512; // 192
    float* pdiff = padv + NADV;                    // 256
    int*   cols  = (int*)(pdiff + NDIF);           // NN*MAXDEG
    int*   cnt   = cols + (size_t)NN * MAXDEG;
    int*   hist  = cnt + NN;
    int*   histT = hist + NN;

    float* Pm = xo;                        // private (set 0)
    float* Sm = xo + (size_t)NN * 512;     // share   (set 1)

    k_init<<<(NN * NTK + 255) / 256, 256, 0, stream>>>(hist, histT);
    k_hist<<<(NELEM + 255) / 256, 256, 0, stream>>>(path, task, hist, histT);
    k_csr<<<NN / 4, 256, 0, stream>>>(adj, cols, cnt);
    k_gemm_wh<<<dim3(NN / 64, SH), 256, 0, stream>>>(feat, Wp, Ws, ap, as_, wh, f1, f2);
    k_gat<<<SH * NN / 4, 256, 0, stream>>>(wh, f1, f2, cols, cnt, xo);
    k_nlogp<<<NADV, 256, 0, stream>>>(Sm, Wsc, bsc, histT, padv);
    k_diff_part<<<dim3(8, 8, KSPLIT), 256, 0, stream>>>(Sm, Pm, hist, Dp);
    k_diff_red<<<NDIF, 256, 0, stream>>>(Dp, pdiff);
    k_scalars<<<1, 256, 0, stream>>>(padv, pdiff, out);
    k_final<<<NPATH, 256, 0, stream>>>(Sm, Pm, path, Wc, bc, out);
}